// Round 1
// baseline (273.772 us; speedup 1.0000x reference)
//
#include <hip/hip_runtime.h>

// SelfAttention (lambda attention) on MI355X.
// Dims: B=8, C=256, H=W=32, n=1024, DK=64, HEADS=4, DQ=256, DV=64.
// SF = 64^-0.25
#define SFC 0.35355339059327373f

__device__ __forceinline__ float4 ld4(const float* p) { return *reinterpret_cast<const float4*>(p); }
__device__ __forceinline__ void st4(float* p, float4 v) { *reinterpret_cast<float4*>(p) = v; }

union F4 { float4 v; float f[4]; };

// ---------------------------------------------------------------------------
// K1: fused projection GEMM.  P[o][col] = sum_c W[o][c] * x[b][c][n],
// col = b*1024+n.  Rows: o<256 -> Wq, 256..319 -> Wk, 320..383 -> Wv.
// ---------------------------------------------------------------------------
__global__ __launch_bounds__(256) void k_proj(
    const float* __restrict__ x, const float* __restrict__ wq,
    const float* __restrict__ wk, const float* __restrict__ wv,
    float* __restrict__ P)
{
  __shared__ float Wt[32][68];   // [k][o] padded
  __shared__ float Xt[32][128];  // [k][n]
  const int t = threadIdx.x;
  const int o0 = blockIdx.x * 64;
  const int col0 = blockIdx.y * 128;
  const int bb = col0 >> 10;
  const int n0 = col0 & 1023;
  const int tr = t >> 4, tc = t & 15;

  const int lr = t >> 2;          // W tile row 0..63
  const int lco = (t & 3) * 8;    // W tile col group
  const int o = o0 + lr;
  const float* wrow = (o < 256) ? (wq + o * 256)
                     : (o < 320) ? (wk + (o - 256) * 256)
                                 : (wv + (o - 320) * 256);
  const int xr = t >> 3;          // X tile row 0..31
  const int xco = (t & 7) * 16;
  const float* xbase = x + bb * (256 * 1024) + n0 + xco;

  float acc[4][8] = {};

  for (int k0 = 0; k0 < 256; k0 += 32) {
    float4 wa = ld4(wrow + k0 + lco);
    float4 wb = ld4(wrow + k0 + lco + 4);
    const float* xp = xbase + (k0 + xr) * 1024;
    float4 x0 = ld4(xp), x1 = ld4(xp + 4), x2 = ld4(xp + 8), x3 = ld4(xp + 12);
    __syncthreads();
    Wt[lco + 0][lr] = wa.x; Wt[lco + 1][lr] = wa.y;
    Wt[lco + 2][lr] = wa.z; Wt[lco + 3][lr] = wa.w;
    Wt[lco + 4][lr] = wb.x; Wt[lco + 5][lr] = wb.y;
    Wt[lco + 6][lr] = wb.z; Wt[lco + 7][lr] = wb.w;
    st4(&Xt[xr][xco], x0); st4(&Xt[xr][xco + 4], x1);
    st4(&Xt[xr][xco + 8], x2); st4(&Xt[xr][xco + 12], x3);
    __syncthreads();
#pragma unroll
    for (int k = 0; k < 32; ++k) {
      F4 av; av.v = ld4(&Wt[k][tr * 4]);
      F4 b0; b0.v = ld4(&Xt[k][tc * 8]);
      F4 b1; b1.v = ld4(&Xt[k][tc * 8 + 4]);
#pragma unroll
      for (int i = 0; i < 4; ++i) {
        const float a = av.f[i];
#pragma unroll
        for (int j = 0; j < 4; ++j) {
          acc[i][j]     += a * b0.f[j];
          acc[i][j + 4] += a * b1.f[j];
        }
      }
    }
  }
#pragma unroll
  for (int i = 0; i < 4; ++i) {
    float* dst = P + (size_t)(o0 + tr * 4 + i) * 8192 + col0 + tc * 8;
    st4(dst,     make_float4(acc[i][0], acc[i][1], acc[i][2], acc[i][3]));
    st4(dst + 4, make_float4(acc[i][4], acc[i][5], acc[i][6], acc[i][7]));
  }
}

// ---------------------------------------------------------------------------
// K2: BN stats per channel (rows 0..319 of P), folded with gamma/beta and SF:
// qs = x*scale + shift  reproduces  SF*((x-mu)*rsqrt(var+eps)*gamma + beta)
// ---------------------------------------------------------------------------
__global__ __launch_bounds__(256) void k_stats(
    const float* __restrict__ P, const float* __restrict__ gq,
    const float* __restrict__ bq, const float* __restrict__ gk,
    const float* __restrict__ bk, float* __restrict__ scale,
    float* __restrict__ shift)
{
  const int ch = blockIdx.x;  // 0..319
  const float4* row = (const float4*)(P + (size_t)ch * 8192);
  float s = 0.f, ss = 0.f;
  for (int i = threadIdx.x; i < 2048; i += 256) {
    float4 v = row[i];
    s  += v.x + v.y + v.z + v.w;
    ss += v.x * v.x + v.y * v.y + v.z * v.z + v.w * v.w;
  }
#pragma unroll
  for (int off = 32; off; off >>= 1) {
    s  += __shfl_down(s, off, 64);
    ss += __shfl_down(ss, off, 64);
  }
  __shared__ float red[8];
  const int w = threadIdx.x >> 6, lane = threadIdx.x & 63;
  if (lane == 0) { red[w] = s; red[4 + w] = ss; }
  __syncthreads();
  if (threadIdx.x == 0) {
    s = red[0] + red[1] + red[2] + red[3];
    ss = red[4] + red[5] + red[6] + red[7];
    const float mu = s * (1.0f / 8192.0f);
    const float var = ss * (1.0f / 8192.0f) - mu * mu;
    const float rsig = rsqrtf(var + 1e-5f);
    float g, be;
    if (ch < 256) { g = gq[ch]; be = bq[ch]; }
    else          { g = gk[ch - 256]; be = bk[ch - 256]; }
    const float sc = rsig * g * SFC;
    scale[ch] = sc;
    shift[ch] = be * SFC - mu * sc;
  }
}

// ---------------------------------------------------------------------------
// K3: softmax over n for each (b, k-channel). Logits = P*scale + shift.
// ---------------------------------------------------------------------------
__global__ __launch_bounds__(256) void k_softmax(
    const float* __restrict__ P, const float* __restrict__ scale,
    const float* __restrict__ shift, float* __restrict__ KS)
{
  const int b = blockIdx.x >> 6, kc = blockIdx.x & 63;
  const int ch = 256 + kc;
  const float4* row = (const float4*)(P + (size_t)ch * 8192 + b * 1024);
  const float sc = scale[ch], sh = shift[ch];
  float4 v = row[threadIdx.x];
  float y0 = v.x * sc + sh, y1 = v.y * sc + sh;
  float y2 = v.z * sc + sh, y3 = v.w * sc + sh;
  float m = fmaxf(fmaxf(y0, y1), fmaxf(y2, y3));
#pragma unroll
  for (int off = 32; off; off >>= 1) m = fmaxf(m, __shfl_xor(m, off, 64));
  __shared__ float red[8];
  const int w = threadIdx.x >> 6, lane = threadIdx.x & 63;
  if (lane == 0) red[w] = m;
  __syncthreads();
  m = fmaxf(fmaxf(red[0], red[1]), fmaxf(red[2], red[3]));
  const float e0 = __expf(y0 - m), e1 = __expf(y1 - m);
  const float e2 = __expf(y2 - m), e3 = __expf(y3 - m);
  float su = e0 + e1 + e2 + e3;
#pragma unroll
  for (int off = 32; off; off >>= 1) su += __shfl_xor(su, off, 64);
  if (lane == 0) red[4 + w] = su;
  __syncthreads();
  const float inv = 1.0f / (red[4] + red[5] + red[6] + red[7]);
  ((float4*)(KS + (size_t)(b * 64 + kc) * 1024))[threadIdx.x] =
      make_float4(e0 * inv, e1 * inv, e2 * inv, e3 * inv);
}

// ---------------------------------------------------------------------------
// K4: content context partials: ctxp[b][nc][kc][vc] = sum_{n in chunk} ks*v
// ---------------------------------------------------------------------------
__global__ __launch_bounds__(256) void k_ctx(
    const float* __restrict__ KS, const float* __restrict__ P,
    float* __restrict__ ctxp)
{
  __shared__ float ksl[64][64];  // [n][kc]
  __shared__ float vl[64][64];   // [n][vc]
  const int t = threadIdx.x;
  const int b = blockIdx.x;
  const int n0 = blockIdx.y * 64;
  {
    const int c = t >> 2, q4 = (t & 3) * 16;
    const float* s = KS + (size_t)(b * 64 + c) * 1024 + n0 + q4;
#pragma unroll
    for (int i = 0; i < 16; ++i) ksl[q4 + i][c] = s[i];
    const float* v = P + (size_t)(320 + c) * 8192 + b * 1024 + n0 + q4;
#pragma unroll
    for (int i = 0; i < 16; ++i) vl[q4 + i][c] = v[i];
  }
  __syncthreads();
  const int tr = t >> 4, tc = t & 15;
  float acc[4][4] = {};
#pragma unroll 4
  for (int nn = 0; nn < 64; ++nn) {
    F4 a; a.v = ld4(&ksl[nn][tr * 4]);
    F4 bv; bv.v = ld4(&vl[nn][tc * 4]);
#pragma unroll
    for (int i = 0; i < 4; ++i)
#pragma unroll
      for (int j = 0; j < 4; ++j) acc[i][j] += a.f[i] * bv.f[j];
  }
  float* dst = ctxp + (size_t)(b * 16 + blockIdx.y) * 4096;
#pragma unroll
  for (int i = 0; i < 4; ++i)
    st4(dst + (tr * 4 + i) * 64 + tc * 4,
        make_float4(acc[i][0], acc[i][1], acc[i][2], acc[i][3]));
}

__global__ __launch_bounds__(256) void k_ctxred(
    const float* __restrict__ ctxp, float* __restrict__ ctx)
{
  const int i = blockIdx.x * 256 + threadIdx.x;  // 32768
  const int b = i >> 12, r = i & 4095;
  float s = 0.f;
#pragma unroll
  for (int c = 0; c < 16; ++c) s += ctxp[(size_t)(b * 16 + c) * 4096 + r];
  ctx[i] = s;
}

// ---------------------------------------------------------------------------
// K5: positional lambda + content epilogue.
// Block = (b, i1, i2-half). S[h,j1,j2] = sum_k q[h,k,j1]*rpe[di+31][dj+31][k],
// out[h,v,j1] += sum_j2 S * v[v,(i2,j2)].  + (half 0) content ctx term.
// ---------------------------------------------------------------------------
extern __shared__ float lds[];

__global__ __launch_bounds__(256) void k_pos(
    const float* __restrict__ P, const float* __restrict__ rpe,
    const float* __restrict__ scale, const float* __restrict__ shift,
    const float* __restrict__ ctx, float* __restrict__ out)
{
  const int t = threadIdx.x;
  const int b = blockIdx.x >> 6;
  const int i1 = (blockIdx.x >> 1) & 31;
  const int half = blockIdx.x & 1;

  float* q_l = lds;            // [k=64][j1=32][h=4]  8192 (also out_l [256][32])
  float* R_l = lds + 8192;     // [dj=63][68]         4284 (also ctx_l [64][64])
  float* V_l = lds + 12476;    // [j2=32][v=64]       2048
  float* S_l = lds + 14524;    // [j1=32][132]        4224 (j2*4+h, padded)

  // stage q (BN+SF folded)
  {
    const int j1 = t & 31, cg = t >> 5;
    const float* src = P + (size_t)b * 1024 + i1 * 32 + j1;
#pragma unroll
    for (int i = 0; i < 32; ++i) {
      const int ch = cg * 32 + i;
      const float v = src[(size_t)ch * 8192] * scale[ch] + shift[ch];
      q_l[(ch & 63) * 128 + j1 * 4 + (ch >> 6)] = v;
    }
  }

  const int j1s = t >> 3;  // 0..31
  const int vg = t & 7;    // v-group (SV) and j2-group (S)
  float oacc[4][8] = {};   // [h][v_idx]

  const int i2lo = half * 16, i2hi = i2lo + 16;
  for (int i2 = i2lo; i2 < i2hi; ++i2) {
    __syncthreads();
    {  // load rpe slice: di = i2 - i1, rows dj=0..62, k=0..63
      const int row = t >> 2, cq = (t & 3) * 16;
      if (row < 63) {
        const float* s = rpe + (size_t)(i2 - i1 + 31) * (63 * 64) + row * 64 + cq;
        float* d = R_l + row * 68 + cq;
#pragma unroll
        for (int i = 0; i < 4; ++i) st4(d + i * 4, ld4(s + i * 4));
      }
    }
    {  // load V rows for key-row i2
      const int j2 = t & 31, vq = t >> 5;
      const float* vp = P + (size_t)320 * 8192 + b * 1024 + i2 * 32 + j2;
#pragma unroll
      for (int i = 0; i < 8; ++i)
        V_l[j2 * 64 + vq * 8 + i] = vp[(size_t)(vq * 8 + i) * 8192];
    }
    __syncthreads();
    {  // S phase: this thread: j1 = j1s, j2 = vg*4..vg*4+3, all 4 heads
      float sacc[4][4] = {};  // [j2i][h]
      const float* rbase = R_l + (vg * 4 - j1s + 31) * 68;
      const float* qb = q_l + j1s * 4;
#pragma unroll
      for (int k0 = 0; k0 < 64; k0 += 4) {
        F4 q0, q1, q2, q3;
        q0.v = ld4(qb + (k0 + 0) * 128);
        q1.v = ld4(qb + (k0 + 1) * 128);
        q2.v = ld4(qb + (k0 + 2) * 128);
        q3.v = ld4(qb + (k0 + 3) * 128);
#pragma unroll
        for (int j2i = 0; j2i < 4; ++j2i) {
          F4 r; r.v = ld4(rbase + j2i * 68 + k0);
#pragma unroll
          for (int h = 0; h < 4; ++h)
            sacc[j2i][h] += r.f[0] * q0.f[h] + r.f[1] * q1.f[h]
                          + r.f[2] * q2.f[h] + r.f[3] * q3.f[h];
        }
      }
#pragma unroll
      for (int j2i = 0; j2i < 4; ++j2i)
        st4(S_l + j1s * 132 + (vg * 4 + j2i) * 4,
            make_float4(sacc[j2i][0], sacc[j2i][1], sacc[j2i][2], sacc[j2i][3]));
    }
    __syncthreads();
    {  // SV phase: out[h, j1s, v] += sum_j2 S[h,j1s,j2] * V[j2,v]
      const float* sb = S_l + j1s * 132;
      const float* vb = V_l + vg * 8;
#pragma unroll 4
      for (int j2 = 0; j2 < 32; ++j2) {
        F4 s4; s4.v = ld4(sb + j2 * 4);
        F4 va; va.v = ld4(vb + j2 * 64);
        F4 vc; vc.v = ld4(vb + j2 * 64 + 4);
#pragma unroll
        for (int h = 0; h < 4; ++h) {
          const float sv = s4.f[h];
#pragma unroll
          for (int j = 0; j < 4; ++j) {
            oacc[h][j]     += sv * va.f[j];
            oacc[h][j + 4] += sv * vc.f[j];
          }
        }
      }
    }
  }

  // content lambda epilogue (half 0 only): out += ctx^T applied to q
  if (half == 0) {
    __syncthreads();
    {
      const int row = t >> 2, cq = (t & 3) * 16;
      const float* cs = ctx + (size_t)b * 4096 + row * 64 + cq;
      float* d = R_l + row * 64 + cq;
#pragma unroll
      for (int i = 0; i < 4; ++i) st4(d + i * 4, ld4(cs + i * 4));
    }
    __syncthreads();
    {
      const float* qb = q_l + j1s * 4;
      const float* cb = R_l + vg * 8;
#pragma unroll 4
      for (int k = 0; k < 64; ++k) {
        F4 q4; q4.v = ld4(qb + k * 128);
        F4 ca; ca.v = ld4(cb + k * 64);
        F4 cc; cc.v = ld4(cb + k * 64 + 4);
#pragma unroll
        for (int h = 0; h < 4; ++h) {
          const float qq = q4.f[h];
#pragma unroll
          for (int j = 0; j < 4; ++j) {
            oacc[h][j]     += qq * ca.f[j];
            oacc[h][j + 4] += qq * cc.f[j];
          }
        }
      }
    }
  }

  __syncthreads();
  float* out_l = q_l;  // [ch=256][j1=32]
#pragma unroll
  for (int h = 0; h < 4; ++h)
#pragma unroll
    for (int j = 0; j < 8; ++j)
      out_l[(h * 64 + vg * 8 + j) * 32 + j1s] = oacc[h][j];
  __syncthreads();
  {
    const int j1 = t & 31, cg = t >> 5;
    float* dst = out + (size_t)b * 262144 + i1 * 32 + j1;
#pragma unroll
    for (int i = 0; i < 32; ++i) {
      const int ch = cg * 32 + i;
      atomicAdd(dst + (size_t)ch * 1024, out_l[ch * 32 + j1]);
    }
  }
}

// ---------------------------------------------------------------------------
extern "C" void kernel_launch(void* const* d_in, const int* in_sizes, int n_in,
                              void* d_out, int out_size, void* d_ws, size_t ws_size,
                              hipStream_t stream) {
  const float* x   = (const float*)d_in[0];
  const float* wq  = (const float*)d_in[1];
  const float* gq  = (const float*)d_in[2];
  const float* bq  = (const float*)d_in[3];
  const float* wk  = (const float*)d_in[4];
  const float* gk  = (const float*)d_in[5];
  const float* bk  = (const float*)d_in[6];
  const float* wv  = (const float*)d_in[7];
  const float* rpe = (const float*)d_in[8];
  float* out = (float*)d_out;
  float* ws = (float*)d_ws;

  float* P     = ws;                 // 384*8192   = 3,145,728
  float* KS    = ws + 3145728;       // 8*64*1024  =   524,288
  float* SCALE = ws + 3670016;       // 320
  float* SHIFT = ws + 3670336;       // 320
  float* CTXP  = ws + 3670656;       // 8*16*4096  =   524,288
  float* CTX   = ws + 4194944;       // 8*64*64    =    32,768

  hipMemsetAsync(d_out, 0, (size_t)out_size * sizeof(float), stream);

  k_proj<<<dim3(6, 64), 256, 0, stream>>>(x, wq, wk, wv, P);
  k_stats<<<320, 256, 0, stream>>>(P, gq, bq, gk, bk, SCALE, SHIFT);
  k_softmax<<<512, 256, 0, stream>>>(P, SCALE, SHIFT, KS);
  k_ctx<<<dim3(8, 16), 256, 0, stream>>>(KS, P, CTXP);
  k_ctxred<<<128, 256, 0, stream>>>(CTXP, CTX);

  hipFuncSetAttribute((const void*)k_pos,
                      hipFuncAttributeMaxDynamicSharedMemorySize, 74992);
  k_pos<<<512, 256, 74992, stream>>>(P, rpe, SCALE, SHIFT, CTX, out);
}

// Round 2
// 86.559 us; speedup vs baseline: 3.1628x; 3.1628x over previous
//
#include <hip/hip_runtime.h>

// SelfAttention (lambda attention) on MI355X.
// B=8, C=256, H=W=32, n=1024, DK=64, HEADS=4, DQ=256, DV=64. SF = 64^-0.25
#define SFC 0.35355339059327373f

typedef __attribute__((ext_vector_type(8))) short short8;
typedef __attribute__((ext_vector_type(16))) float f32x16;

__device__ __forceinline__ float4 ld4(const float* p) { return *reinterpret_cast<const float4*>(p); }
__device__ __forceinline__ void st4(float* p, float4 v) { *reinterpret_cast<float4*>(p) = v; }

union F4 { float4 v; float f[4]; };
union S8 { short8 v; unsigned short u[8]; };

__device__ __forceinline__ unsigned short bfb(float f) {
  union { float f; unsigned u; } a; a.f = f;
  unsigned r = a.u + 0x7FFFu + ((a.u >> 16) & 1u);   // RNE f32->bf16
  return (unsigned short)(r >> 16);
}

// ---------------------------------------------------------------------------
// K1: fused projection GEMM.  P[o][col] = sum_c W[o][c] * x[b][c][n],
// col = b*1024+n.  Rows: o<256 -> Wq, 256..319 -> Wk, 320..383 -> Wv.
// ---------------------------------------------------------------------------
__global__ __launch_bounds__(256) void k_proj(
    const float* __restrict__ x, const float* __restrict__ wq,
    const float* __restrict__ wk, const float* __restrict__ wv,
    float* __restrict__ P)
{
  __shared__ float Wt[32][68];   // [k][o] padded
  __shared__ float Xt[32][128];  // [k][n]
  const int t = threadIdx.x;
  const int o0 = blockIdx.x * 64;
  const int col0 = blockIdx.y * 128;
  const int bb = col0 >> 10;
  const int n0 = col0 & 1023;
  const int tr = t >> 4, tc = t & 15;

  const int lr = t >> 2;          // W tile row 0..63
  const int lco = (t & 3) * 8;    // W tile col group
  const int o = o0 + lr;
  const float* wrow = (o < 256) ? (wq + o * 256)
                     : (o < 320) ? (wk + (o - 256) * 256)
                                 : (wv + (o - 320) * 256);
  const int xr = t >> 3;          // X tile row 0..31
  const int xco = (t & 7) * 16;
  const float* xbase = x + bb * (256 * 1024) + n0 + xco;

  float acc[4][8] = {};

  for (int k0 = 0; k0 < 256; k0 += 32) {
    float4 wa = ld4(wrow + k0 + lco);
    float4 wb = ld4(wrow + k0 + lco + 4);
    const float* xp = xbase + (k0 + xr) * 1024;
    float4 x0 = ld4(xp), x1 = ld4(xp + 4), x2 = ld4(xp + 8), x3 = ld4(xp + 12);
    __syncthreads();
    Wt[lco + 0][lr] = wa.x; Wt[lco + 1][lr] = wa.y;
    Wt[lco + 2][lr] = wa.z; Wt[lco + 3][lr] = wa.w;
    Wt[lco + 4][lr] = wb.x; Wt[lco + 5][lr] = wb.y;
    Wt[lco + 6][lr] = wb.z; Wt[lco + 7][lr] = wb.w;
    st4(&Xt[xr][xco], x0); st4(&Xt[xr][xco + 4], x1);
    st4(&Xt[xr][xco + 8], x2); st4(&Xt[xr][xco + 12], x3);
    __syncthreads();
#pragma unroll
    for (int k = 0; k < 32; ++k) {
      F4 av; av.v = ld4(&Wt[k][tr * 4]);
      F4 b0; b0.v = ld4(&Xt[k][tc * 8]);
      F4 b1; b1.v = ld4(&Xt[k][tc * 8 + 4]);
#pragma unroll
      for (int i = 0; i < 4; ++i) {
        const float a = av.f[i];
#pragma unroll
        for (int j = 0; j < 4; ++j) {
          acc[i][j]     += a * b0.f[j];
          acc[i][j + 4] += a * b1.f[j];
        }
      }
    }
  }
#pragma unroll
  for (int i = 0; i < 4; ++i) {
    float* dst = P + (size_t)(o0 + tr * 4 + i) * 8192 + col0 + tc * 8;
    st4(dst,     make_float4(acc[i][0], acc[i][1], acc[i][2], acc[i][3]));
    st4(dst + 4, make_float4(acc[i][4], acc[i][5], acc[i][6], acc[i][7]));
  }
}

// ---------------------------------------------------------------------------
// K2: BN stats per channel, folded with gamma/beta and SF.
// ---------------------------------------------------------------------------
__global__ __launch_bounds__(256) void k_stats(
    const float* __restrict__ P, const float* __restrict__ gq,
    const float* __restrict__ bq, const float* __restrict__ gk,
    const float* __restrict__ bk, float* __restrict__ scale,
    float* __restrict__ shift)
{
  const int ch = blockIdx.x;  // 0..319
  const float4* row = (const float4*)(P + (size_t)ch * 8192);
  float s = 0.f, ss = 0.f;
  for (int i = threadIdx.x; i < 2048; i += 256) {
    float4 v = row[i];
    s  += v.x + v.y + v.z + v.w;
    ss += v.x * v.x + v.y * v.y + v.z * v.z + v.w * v.w;
  }
#pragma unroll
  for (int off = 32; off; off >>= 1) {
    s  += __shfl_down(s, off, 64);
    ss += __shfl_down(ss, off, 64);
  }
  __shared__ float red[8];
  const int w = threadIdx.x >> 6, lane = threadIdx.x & 63;
  if (lane == 0) { red[w] = s; red[4 + w] = ss; }
  __syncthreads();
  if (threadIdx.x == 0) {
    s = red[0] + red[1] + red[2] + red[3];
    ss = red[4] + red[5] + red[6] + red[7];
    const float mu = s * (1.0f / 8192.0f);
    const float var = ss * (1.0f / 8192.0f) - mu * mu;
    const float rsig = rsqrtf(var + 1e-5f);
    float g, be;
    if (ch < 256) { g = gq[ch]; be = bq[ch]; }
    else          { g = gk[ch - 256]; be = bk[ch - 256]; }
    const float sc = rsig * g * SFC;
    scale[ch] = sc;
    shift[ch] = be * SFC - mu * sc;
  }
}

// ---------------------------------------------------------------------------
// K3: softmax over n for each (b, k-channel).
// ---------------------------------------------------------------------------
__global__ __launch_bounds__(256) void k_softmax(
    const float* __restrict__ P, const float* __restrict__ scale,
    const float* __restrict__ shift, float* __restrict__ KS)
{
  const int b = blockIdx.x >> 6, kc = blockIdx.x & 63;
  const int ch = 256 + kc;
  const float4* row = (const float4*)(P + (size_t)ch * 8192 + b * 1024);
  const float sc = scale[ch], sh = shift[ch];
  float4 v = row[threadIdx.x];
  float y0 = v.x * sc + sh, y1 = v.y * sc + sh;
  float y2 = v.z * sc + sh, y3 = v.w * sc + sh;
  float m = fmaxf(fmaxf(y0, y1), fmaxf(y2, y3));
#pragma unroll
  for (int off = 32; off; off >>= 1) m = fmaxf(m, __shfl_xor(m, off, 64));
  __shared__ float red[8];
  const int w = threadIdx.x >> 6, lane = threadIdx.x & 63;
  if (lane == 0) red[w] = m;
  __syncthreads();
  m = fmaxf(fmaxf(red[0], red[1]), fmaxf(red[2], red[3]));
  const float e0 = __expf(y0 - m), e1 = __expf(y1 - m);
  const float e2 = __expf(y2 - m), e3 = __expf(y3 - m);
  float su = e0 + e1 + e2 + e3;
#pragma unroll
  for (int off = 32; off; off >>= 1) su += __shfl_xor(su, off, 64);
  if (lane == 0) red[4 + w] = su;
  __syncthreads();
  const float inv = 1.0f / (red[4] + red[5] + red[6] + red[7]);
  ((float4*)(KS + (size_t)(b * 64 + kc) * 1024))[threadIdx.x] =
      make_float4(e0 * inv, e1 * inv, e2 * inv, e3 * inv);
}

// ---------------------------------------------------------------------------
// K4: content context partials: ctxp[b][nc][kc][vc] = sum_{n in chunk} ks*v
// ---------------------------------------------------------------------------
__global__ __launch_bounds__(256) void k_ctx(
    const float* __restrict__ KS, const float* __restrict__ P,
    float* __restrict__ ctxp)
{
  __shared__ float ksl[64][64];  // [n][kc]
  __shared__ float vl[64][64];   // [n][vc]
  const int t = threadIdx.x;
  const int b = blockIdx.x;
  const int n0 = blockIdx.y * 64;
  {
    const int c = t >> 2, q4 = (t & 3) * 16;
    const float* s = KS + (size_t)(b * 64 + c) * 1024 + n0 + q4;
#pragma unroll
    for (int i = 0; i < 16; ++i) ksl[q4 + i][c] = s[i];
    const float* v = P + (size_t)(320 + c) * 8192 + b * 1024 + n0 + q4;
#pragma unroll
    for (int i = 0; i < 16; ++i) vl[q4 + i][c] = v[i];
  }
  __syncthreads();
  const int tr = t >> 4, tc = t & 15;
  float acc[4][4] = {};
#pragma unroll 4
  for (int nn = 0; nn < 64; ++nn) {
    F4 a; a.v = ld4(&ksl[nn][tr * 4]);
    F4 bv; bv.v = ld4(&vl[nn][tc * 4]);
#pragma unroll
    for (int i = 0; i < 4; ++i)
#pragma unroll
      for (int j = 0; j < 4; ++j) acc[i][j] += a.f[i] * bv.f[j];
  }
  float* dst = ctxp + (size_t)(b * 16 + blockIdx.y) * 4096;
#pragma unroll
  for (int i = 0; i < 4; ++i)
    st4(dst + (tr * 4 + i) * 64 + tc * 4,
        make_float4(acc[i][0], acc[i][1], acc[i][2], acc[i][3]));
}

// reduce partials; write TRANSPOSED ctx: CTXT[b][v][k]
__global__ __launch_bounds__(256) void k_ctxred(
    const float* __restrict__ ctxp, float* __restrict__ ctxt)
{
  const int i = blockIdx.x * 256 + threadIdx.x;  // 32768
  const int b = i >> 12, r = i & 4095, kc = r >> 6, vc = r & 63;
  float s = 0.f;
#pragma unroll
  for (int c = 0; c < 16; ++c) s += ctxp[(size_t)(b * 16 + c) * 4096 + r];
  ctxt[(size_t)b * 4096 + vc * 64 + kc] = s;
}

// ---------------------------------------------------------------------------
// K5: positional lambda via MFMA + content epilogue, block = (b, i1).
// 8 waves: wave w -> head m = w&3, N-tile nt = w>>2.
// Per i2: T[j1,dj] = q^T * rpe[di]  (GEMM M32 N64 K64, bf16 MFMA)
//         shear  S[j1, dj+j1-31] = T[j1,dj]  (masked b16 LDS writes)
//         out[j1,v] += S * V       (GEMM M32 N64 K32)
// Epilogue: out[j1,v] += q^T * ctx (GEMM M32 N64 K64); coalesced store.
// ---------------------------------------------------------------------------
extern __shared__ char ldsc[];

__device__ __forceinline__ void stage_issue(const float* __restrict__ rpe_di,
    const float* __restrict__ Pv, int t, int i2,
    float4& ra0, float4& ra1, float4& rv)
{
  if (t < 504) {
    const float* rp = rpe_di + (t >> 3) * 64 + (t & 7) * 8;
    ra0 = ld4(rp); ra1 = ld4(rp + 4);
  }
  rv = ld4(Pv + (size_t)(t >> 3) * 8192 + i2 * 32 + (t & 7) * 4);
}

__device__ __forceinline__ void stage_commit(unsigned short* __restrict__ Rb,
    unsigned short* __restrict__ Vb, int t,
    float4 ra0, float4 ra1, float4 rv)
{
  if (t < 504) {
    S8 s;
    s.u[0] = bfb(ra0.x); s.u[1] = bfb(ra0.y); s.u[2] = bfb(ra0.z); s.u[3] = bfb(ra0.w);
    s.u[4] = bfb(ra1.x); s.u[5] = bfb(ra1.y); s.u[6] = bfb(ra1.z); s.u[7] = bfb(ra1.w);
    *(short8*)(Rb + (t >> 3) * 72 + (t & 7) * 8) = s.v;
  }
  ushort4 u;
  u.x = bfb(rv.x); u.y = bfb(rv.y); u.z = bfb(rv.z); u.w = bfb(rv.w);
  *(ushort4*)(Vb + (t >> 3) * 40 + (t & 7) * 4) = u;
}

__global__ __launch_bounds__(512) void k_pos(
    const float* __restrict__ P, const float* __restrict__ rpe,
    const float* __restrict__ scale, const float* __restrict__ shift,
    const float* __restrict__ ctxt, float* __restrict__ out)
{
  float* qst = (float*)ldsc;                                        // [256][33] f32, 33792 B
  unsigned short* Rb = (unsigned short*)(ldsc + 33792);             // 2 x [64][72] bf16, 18432 B
  unsigned short* Vb = (unsigned short*)(ldsc + 33792 + 18432);     // 2 x [64][40] bf16, 10240 B
  unsigned short* Sl = (unsigned short*)(ldsc + 33792 + 18432 + 10240); // 4 x [32][40] bf16, 10240 B

  const int t = threadIdx.x;
  const int b = blockIdx.x >> 5, i1 = blockIdx.x & 31;
  const int w = t >> 6, l = t & 63, ln = l & 31, hi = l >> 5;
  const int m = w & 3, nt = w >> 2;

  // ---- stage scaled q [256 ch][32 j1] into LDS (f32) ----
  {
    const int j1 = t & 31, c0 = (t >> 5) * 16;
    const float* src = P + (size_t)b * 1024 + i1 * 32 + j1;
#pragma unroll
    for (int i = 0; i < 16; ++i) {
      const int ch = c0 + i;
      qst[ch * 33 + j1] = src[(size_t)ch * 8192] * scale[ch] + shift[ch];
    }
  }
  __syncthreads();

  // ---- build per-wave q A-fragments: lane: row j1=ln, k = ks*16 + hi*8 + i ----
  short8 qf0, qf1, qf2, qf3;
  {
    S8 s;
#pragma unroll
    for (int i = 0; i < 8; ++i) s.u[i] = bfb(qst[(m * 64 + 0  + hi * 8 + i) * 33 + ln]);
    qf0 = s.v;
#pragma unroll
    for (int i = 0; i < 8; ++i) s.u[i] = bfb(qst[(m * 64 + 16 + hi * 8 + i) * 33 + ln]);
    qf1 = s.v;
#pragma unroll
    for (int i = 0; i < 8; ++i) s.u[i] = bfb(qst[(m * 64 + 32 + hi * 8 + i) * 33 + ln]);
    qf2 = s.v;
#pragma unroll
    for (int i = 0; i < 8; ++i) s.u[i] = bfb(qst[(m * 64 + 48 + hi * 8 + i) * 33 + ln]);
    qf3 = s.v;
  }

  const float* Pv = P + (size_t)320 * 8192 + b * 1024;
  float4 ra0, ra1, rv;

  // prologue stage i2=0 into buf 0
  stage_issue(rpe + (size_t)(0 - i1 + 31) * 4032, Pv, t, 0, ra0, ra1, rv);
  stage_commit(Rb, Vb, t, ra0, ra1, rv);
  __syncthreads();

  f32x16 sv;
#pragma unroll
  for (int i = 0; i < 16; ++i) sv[i] = 0.f;

  for (int s = 0; s < 32; ++s) {
    const int cur = s & 1;
    if (s + 1 < 32)
      stage_issue(rpe + (size_t)(s + 1 - i1 + 31) * 4032, Pv, t, s + 1, ra0, ra1, rv);

    // T-GEMM: D[j1, dj-tile nt] = sum_k q * R
    f32x16 tac;
#pragma unroll
    for (int i = 0; i < 16; ++i) tac[i] = 0.f;
    {
      const unsigned short* rb = Rb + cur * 4608 + (nt * 32 + ln) * 72 + hi * 8;
      tac = __builtin_amdgcn_mfma_f32_32x32x16_bf16(qf0, *(const short8*)(rb +  0), tac, 0, 0, 0);
      tac = __builtin_amdgcn_mfma_f32_32x32x16_bf16(qf1, *(const short8*)(rb + 16), tac, 0, 0, 0);
      tac = __builtin_amdgcn_mfma_f32_32x32x16_bf16(qf2, *(const short8*)(rb + 32), tac, 0, 0, 0);
      tac = __builtin_amdgcn_mfma_f32_32x32x16_bf16(qf3, *(const short8*)(rb + 48), tac, 0, 0, 0);
    }
    // shear: S[j1][j2 = dj + j1 - 31] = T[j1][dj]
    {
      unsigned short* sm = Sl + m * 1280;
      const int dj = nt * 32 + ln;
#pragma unroll
      for (int r = 0; r < 16; ++r) {
        const int j1 = (r & 3) + 8 * (r >> 2) + 4 * hi;
        const int j2 = dj + j1 - 31;
        if ((unsigned)j2 < 32u) sm[j1 * 40 + j2] = bfb(tac[r]);
      }
    }
    __syncthreads();
    // SV: out[j1, v-tile nt] += S * V
    {
      const unsigned short* sa = Sl + m * 1280 + ln * 40 + hi * 8;
      const unsigned short* vb = Vb + cur * 2560 + (nt * 32 + ln) * 40 + hi * 8;
      sv = __builtin_amdgcn_mfma_f32_32x32x16_bf16(*(const short8*)(sa),      *(const short8*)(vb),      sv, 0, 0, 0);
      sv = __builtin_amdgcn_mfma_f32_32x32x16_bf16(*(const short8*)(sa + 16), *(const short8*)(vb + 16), sv, 0, 0, 0);
    }
    if (s + 1 < 32) stage_commit(Rb + (cur ^ 1) * 4608, Vb + (cur ^ 1) * 2560, t, ra0, ra1, rv);
    __syncthreads();
  }

  // ---- content epilogue: stage ctx^T [v][k] bf16 into Rb buf0 ----
  {
    const int v = t >> 3, k0 = (t & 7) * 8;
    const float* cs = ctxt + (size_t)b * 4096 + v * 64 + k0;
    float4 c0 = ld4(cs), c1 = ld4(cs + 4);
    S8 s;
    s.u[0] = bfb(c0.x); s.u[1] = bfb(c0.y); s.u[2] = bfb(c0.z); s.u[3] = bfb(c0.w);
    s.u[4] = bfb(c1.x); s.u[5] = bfb(c1.y); s.u[6] = bfb(c1.z); s.u[7] = bfb(c1.w);
    *(short8*)(Rb + v * 72 + k0) = s.v;
  }
  __syncthreads();
  {
    const unsigned short* cb = Rb + (nt * 32 + ln) * 72 + hi * 8;
    sv = __builtin_amdgcn_mfma_f32_32x32x16_bf16(qf0, *(const short8*)(cb +  0), sv, 0, 0, 0);
    sv = __builtin_amdgcn_mfma_f32_32x32x16_bf16(qf1, *(const short8*)(cb + 16), sv, 0, 0, 0);
    sv = __builtin_amdgcn_mfma_f32_32x32x16_bf16(qf2, *(const short8*)(cb + 32), sv, 0, 0, 0);
    sv = __builtin_amdgcn_mfma_f32_32x32x16_bf16(qf3, *(const short8*)(cb + 48), sv, 0, 0, 0);
  }

  // ---- write acc -> qst [ch][33], then coalesced global store ----
  {
    const int ch = m * 64 + nt * 32 + ln;
#pragma unroll
    for (int r = 0; r < 16; ++r) {
      const int j1 = (r & 3) + 8 * (r >> 2) + 4 * hi;
      qst[ch * 33 + j1] = sv[r];
    }
  }
  __syncthreads();
  {
    const int ch = t >> 1, jh = (t & 1) * 16;
    const float* srow = qst + ch * 33 + jh;
    float* dst = out + (size_t)b * 262144 + (size_t)ch * 1024 + i1 * 32 + jh;
#pragma unroll
    for (int g = 0; g < 4; ++g)
      st4(dst + g * 4, make_float4(srow[g * 4], srow[g * 4 + 1],
                                   srow[g * 4 + 2], srow[g * 4 + 3]));
  }
}

// ---------------------------------------------------------------------------
extern "C" void kernel_launch(void* const* d_in, const int* in_sizes, int n_in,
                              void* d_out, int out_size, void* d_ws, size_t ws_size,
                              hipStream_t stream) {
  const float* x   = (const float*)d_in[0];
  const float* wq  = (const float*)d_in[1];
  const float* gq  = (const float*)d_in[2];
  const float* bq  = (const float*)d_in[3];
  const float* wk  = (const float*)d_in[4];
  const float* gk  = (const float*)d_in[5];
  const float* bk  = (const float*)d_in[6];
  const float* wv  = (const float*)d_in[7];
  const float* rpe = (const float*)d_in[8];
  float* out = (float*)d_out;
  float* ws = (float*)d_ws;

  float* P     = ws;                 // 384*8192   = 3,145,728 floats
  float* KS    = ws + 3145728;       // 8*64*1024  =   524,288
  float* SCALE = ws + 3670016;       // 320
  float* SHIFT = ws + 3670336;       // 320
  float* CTXP  = ws + 3670656;       // 8*16*4096  =   524,288
  float* CTXT  = KS;                 // KS dead after k_ctx; reuse for ctx^T (32768)

  k_proj<<<dim3(6, 64), 256, 0, stream>>>(x, wq, wk, wv, P);
  k_stats<<<320, 256, 0, stream>>>(P, gq, bq, gk, bk, SCALE, SHIFT);
  k_softmax<<<512, 256, 0, stream>>>(P, SCALE, SHIFT, KS);
  k_ctx<<<dim3(8, 16), 256, 0, stream>>>(KS, P, CTXP);
  k_ctxred<<<128, 256, 0, stream>>>(CTXP, CTXT);

  hipFuncSetAttribute((const void*)k_pos,
                      hipFuncAttributeMaxDynamicSharedMemorySize, 72704);
  k_pos<<<256, 512, 72704, stream>>>(P, rpe, SCALE, SHIFT, CTXT, out);
}